// Round 1
// baseline (2603.781 us; speedup 1.0000x reference)
//
#include <hip/hip_runtime.h>
#include <hip/hip_bf16.h>
#include <math.h>

#define D_ 512
#define K_ 8
#define L_ 64
#define Q_ 4096
#define C_ 4096
#define N_ (C_ * K_)   // 32768 columns of the fused bilinear GEMM

#define TS 64
#define BK 16

// ---------------------------------------------------------------------------
// Kernel 1: transpose M[i,j,k] (strides D*K, K, 1) -> Mt[k][i][j]
// ---------------------------------------------------------------------------
__global__ void transpose_M(const float* __restrict__ M, float* __restrict__ Mt) {
    int idx = blockIdx.x * blockDim.x + threadIdx.x;   // over D*D*K, output index
    // output: k*D*D + i*D + j
    int j = idx % D_;
    int i = (idx / D_) % D_;
    int k = idx / (D_ * D_);
    Mt[idx] = M[(i * D_ + j) * K_ + k];
}

// ---------------------------------------------------------------------------
// Kernel 2: P[c][k*D + j] = sum_i class[c,i] * Mt[k][i][j]
// NN GEMM: A = class [C x D], B-slab = Mt[k] [D x D]. Tile 64x64, BK=16.
// ---------------------------------------------------------------------------
__launch_bounds__(256)
__global__ void gemm_P(const float* __restrict__ A,   // class [C][D]
                       const float* __restrict__ Mt,  // [K][D][D]
                       float* __restrict__ P) {       // [C][K*D]
    __shared__ float As[BK][TS];   // As[i_local][c_local]
    __shared__ float Bs[BK][TS];   // Bs[i_local][j_local]
    const int n0 = blockIdx.x * TS;      // over K*D
    const int c0 = blockIdx.y * TS;
    const int kslab = n0 / D_;
    const int j0 = n0 % D_;
    const float* B = Mt + (size_t)kslab * D_ * D_;
    const int tid = threadIdx.x;
    const int tx = tid % 16, ty = tid / 16;
    float acc[4][4] = {};
    for (int i0 = 0; i0 < D_; i0 += BK) {
        {   // A tile: 64 rows (c) x 16 cols (i) -> As[i][c]
            int r = tid / 4, cg = tid % 4;
            const float4 av = *(const float4*)&A[(size_t)(c0 + r) * D_ + i0 + cg * 4];
            As[cg * 4 + 0][r] = av.x; As[cg * 4 + 1][r] = av.y;
            As[cg * 4 + 2][r] = av.z; As[cg * 4 + 3][r] = av.w;
        }
        {   // B tile: 16 rows (i) x 64 cols (j) -> Bs[i][j]
            int r = tid / 16, cg = tid % 16;
            const float4 bv = *(const float4*)&B[(size_t)(i0 + r) * D_ + j0 + cg * 4];
            *(float4*)&Bs[r][cg * 4] = bv;
        }
        __syncthreads();
#pragma unroll
        for (int i = 0; i < BK; ++i) {
            float4 a = *(const float4*)&As[i][ty * 4];
            float4 b = *(const float4*)&Bs[i][tx * 4];
            float av[4] = {a.x, a.y, a.z, a.w};
            float bv[4] = {b.x, b.y, b.z, b.w};
#pragma unroll
            for (int u = 0; u < 4; ++u)
#pragma unroll
                for (int v = 0; v < 4; ++v) acc[u][v] += av[u] * bv[v];
        }
        __syncthreads();
    }
#pragma unroll
    for (int u = 0; u < 4; ++u) {
        float4 o = {acc[u][0], acc[u][1], acc[u][2], acc[u][3]};
        *(float4*)&P[(size_t)(c0 + ty * 4 + u) * (K_ * D_) + n0 + tx * 4] = o;
    }
}

// ---------------------------------------------------------------------------
// Kernel 3: fused bilinear + relu + score reduction.
// other[q][c] = sb + sum_k sw[k] * relu( sum_j query[q][j] * P[c][k][j] )
// NT GEMM: A = query [Q][D], Bt = P viewed as [N=C*K][D]. Tile 64x64 (=8 c's).
// ---------------------------------------------------------------------------
__launch_bounds__(256)
__global__ void bilinear_score(const float* __restrict__ Qv,  // [Q][D]
                               const float* __restrict__ P,   // [N][D]
                               const float* __restrict__ sw,  // [K]
                               const float* __restrict__ sb,  // [1]
                               float* __restrict__ other) {   // [Q][C]
    __shared__ float As[BK][TS];   // As[j_local][q_local]
    __shared__ float Bs[BK][TS];   // Bs[j_local][m_local]
    const int m0 = blockIdx.x * TS;   // over N
    const int q0 = blockIdx.y * TS;
    const int tid = threadIdx.x;
    const int tx = tid % 16, ty = tid / 16;
    float acc[4][4] = {};
    for (int j0 = 0; j0 < D_; j0 += BK) {
        int r = tid / 4, cg = tid % 4;
        {   // A tile: 64 rows (q) x 16 cols (j) -> As[j][q]
            const float4 av = *(const float4*)&Qv[(size_t)(q0 + r) * D_ + j0 + cg * 4];
            As[cg * 4 + 0][r] = av.x; As[cg * 4 + 1][r] = av.y;
            As[cg * 4 + 2][r] = av.z; As[cg * 4 + 3][r] = av.w;
        }
        {   // B tile: 64 rows (m) x 16 cols (j) -> Bs[j][m]
            const float4 bv = *(const float4*)&P[(size_t)(m0 + r) * D_ + j0 + cg * 4];
            Bs[cg * 4 + 0][r] = bv.x; Bs[cg * 4 + 1][r] = bv.y;
            Bs[cg * 4 + 2][r] = bv.z; Bs[cg * 4 + 3][r] = bv.w;
        }
        __syncthreads();
#pragma unroll
        for (int j = 0; j < BK; ++j) {
            float4 a = *(const float4*)&As[j][ty * 4];
            float4 b = *(const float4*)&Bs[j][tx * 4];
            float av[4] = {a.x, a.y, a.z, a.w};
            float bv[4] = {b.x, b.y, b.z, b.w};
#pragma unroll
            for (int u = 0; u < 4; ++u)
#pragma unroll
                for (int v = 0; v < 4; ++v) acc[u][v] += av[u] * bv[v];
        }
        __syncthreads();
    }
    // Epilogue: this thread's 4 columns are m = m0 + tx*4 + v.
    // k = m % 8. tx even -> k in {0..3}, tx odd -> k in {4..7} of the same c.
    float w[4];
#pragma unroll
    for (int v = 0; v < 4; ++v) w[v] = sw[(tx * 4 + v) % K_];
    const float bias = sb[0];
#pragma unroll
    for (int u = 0; u < 4; ++u) {
        float part = 0.f;
#pragma unroll
        for (int v = 0; v < 4; ++v) part += w[v] * fmaxf(acc[u][v], 0.f);
        part += __shfl_xor(part, 1);   // combine k 0-3 with k 4-7 (lanes tid, tid^1)
        if ((tx & 1) == 0) {
            int c = (m0 + tx * 4) / K_;
            other[(size_t)(q0 + ty * 4 + u) * C_ + c] = part + bias;
        }
    }
}

// ---------------------------------------------------------------------------
// Kernel 4: in-place row softmax over C.
// ---------------------------------------------------------------------------
__launch_bounds__(256)
__global__ void softmax_rows(float* __restrict__ base) {
    const int q = blockIdx.x;
    float* row = base + (size_t)q * C_;
    const int tid = threadIdx.x;
    __shared__ float red[4];
    float m = -1e30f;
    for (int i = tid; i < C_; i += 256) m = fmaxf(m, row[i]);
#pragma unroll
    for (int off = 32; off; off >>= 1) m = fmaxf(m, __shfl_down(m, off));
    if ((tid & 63) == 0) red[tid >> 6] = m;
    __syncthreads();
    m = fmaxf(fmaxf(red[0], red[1]), fmaxf(red[2], red[3]));
    __syncthreads();
    float s = 0.f;
    for (int i = tid; i < C_; i += 256) {
        float e = __expf(row[i] - m);
        row[i] = e;
        s += e;
    }
#pragma unroll
    for (int off = 32; off; off >>= 1) s += __shfl_down(s, off);
    if ((tid & 63) == 0) red[tid >> 6] = s;
    __syncthreads();
    const float inv = 1.f / (red[0] + red[1] + red[2] + red[3]);
    for (int i = tid; i < C_; i += 256) row[i] *= inv;
}

// ---------------------------------------------------------------------------
// Kernel 5: qf[q][d] = sum_c probs[q][c] * class[c][d] + query[q][d]
// NN GEMM [QxC]@[CxD], tile 64x64, BK=16.
// ---------------------------------------------------------------------------
__launch_bounds__(256)
__global__ void gemm_qf(const float* __restrict__ A,   // probs [Q][C]
                        const float* __restrict__ B,   // class [C][D]
                        const float* __restrict__ Qv,  // query [Q][D]
                        float* __restrict__ qf) {      // [Q][D]
    __shared__ float As[BK][TS];
    __shared__ float Bs[BK][TS];
    const int d0 = blockIdx.x * TS;
    const int q0 = blockIdx.y * TS;
    const int tid = threadIdx.x;
    const int tx = tid % 16, ty = tid / 16;
    float acc[4][4] = {};
    for (int c0 = 0; c0 < C_; c0 += BK) {
        {   // A tile: 64 rows (q) x 16 cols (c) -> As[c][q]
            int r = tid / 4, cg = tid % 4;
            const float4 av = *(const float4*)&A[(size_t)(q0 + r) * C_ + c0 + cg * 4];
            As[cg * 4 + 0][r] = av.x; As[cg * 4 + 1][r] = av.y;
            As[cg * 4 + 2][r] = av.z; As[cg * 4 + 3][r] = av.w;
        }
        {   // B tile: 16 rows (c) x 64 cols (d) -> Bs[c][d]
            int r = tid / 16, cg = tid % 16;
            const float4 bv = *(const float4*)&B[(size_t)(c0 + r) * D_ + d0 + cg * 4];
            *(float4*)&Bs[r][cg * 4] = bv;
        }
        __syncthreads();
#pragma unroll
        for (int i = 0; i < BK; ++i) {
            float4 a = *(const float4*)&As[i][ty * 4];
            float4 b = *(const float4*)&Bs[i][tx * 4];
            float av[4] = {a.x, a.y, a.z, a.w};
            float bv[4] = {b.x, b.y, b.z, b.w};
#pragma unroll
            for (int u = 0; u < 4; ++u)
#pragma unroll
                for (int v = 0; v < 4; ++v) acc[u][v] += av[u] * bv[v];
        }
        __syncthreads();
    }
#pragma unroll
    for (int u = 0; u < 4; ++u) {
        const int q = q0 + ty * 4 + u;
        const float4 qv = *(const float4*)&Qv[(size_t)q * D_ + d0 + tx * 4];
        float4 o = {acc[u][0] + qv.x, acc[u][1] + qv.y,
                    acc[u][2] + qv.z, acc[u][3] + qv.w};
        *(float4*)&qf[(size_t)q * D_ + d0 + tx * 4] = o;
    }
}

// ---------------------------------------------------------------------------
// Kernel 6: hash[q][l] = tanh( sum_d qf[q][d]*hash_w[l][d] + hash_b[l] )
// 4 q per block; qf rows staged in LDS.
// ---------------------------------------------------------------------------
__launch_bounds__(256)
__global__ void hash_kernel(const float* __restrict__ qf,
                            const float* __restrict__ hw,   // [L][D]
                            const float* __restrict__ hb,   // [L]
                            float* __restrict__ out) {      // [Q][L]
    __shared__ float sqf[4 * D_];
    const int q0 = blockIdx.x * 4;
    const int tid = threadIdx.x;
    {
        const float4* src = (const float4*)&qf[(size_t)q0 * D_];
        float4* dst = (float4*)sqf;
#pragma unroll
        for (int it = 0; it < 2; ++it) dst[tid + it * 256] = src[tid + it * 256];
    }
    __syncthreads();
    const int l = tid % L_;
    const int qi = tid / L_;
    float s = hb[l];
    const float* wrow = &hw[(size_t)l * D_];
    const float* xrow = &sqf[qi * D_];
#pragma unroll 4
    for (int d = 0; d < D_; d += 4) {
        float4 w4 = *(const float4*)&wrow[d];
        float4 x4 = *(const float4*)&xrow[d];
        s += x4.x * w4.x + x4.y * w4.y + x4.z * w4.z + x4.w * w4.w;
    }
    out[(size_t)(q0 + qi) * L_ + l] = tanhf(s);
}

// ---------------------------------------------------------------------------
extern "C" void kernel_launch(void* const* d_in, const int* in_sizes, int n_in,
                              void* d_out, int out_size, void* d_ws, size_t ws_size,
                              hipStream_t stream) {
    const float* class_v = (const float*)d_in[0];   // [C][D]
    const float* query_v = (const float*)d_in[1];   // [Q][D]
    const float* M       = (const float*)d_in[2];   // [D][D][K]
    const float* score_w = (const float*)d_in[3];   // [K]
    const float* score_b = (const float*)d_in[4];   // [1]
    const float* hash_w  = (const float*)d_in[5];   // [L][D]
    const float* hash_b  = (const float*)d_in[6];   // [L]
    float* out = (float*)d_out;                     // [Q][L]

    float* ws = (float*)d_ws;
    float* P     = ws;                               // C*K*D  = 16,777,216 floats
    float* other = P + (size_t)C_ * K_ * D_;         // Q*C    = 16,777,216 floats
    float* scratch = other + (size_t)Q_ * C_;        // 2,097,152 floats (Mt then qf)
    float* Mt = scratch;
    float* qf = scratch;

    transpose_M<<<(D_ * D_ * K_) / 256, 256, 0, stream>>>(M, Mt);
    gemm_P<<<dim3((K_ * D_) / TS, C_ / TS), 256, 0, stream>>>(class_v, Mt, P);
    bilinear_score<<<dim3(N_ / TS, Q_ / TS), 256, 0, stream>>>(query_v, P, score_w, score_b, other);
    softmax_rows<<<Q_, 256, 0, stream>>>(other);
    gemm_qf<<<dim3(D_ / TS, Q_ / TS), 256, 0, stream>>>(other, class_v, query_v, qf);
    hash_kernel<<<Q_ / 4, 256, 0, stream>>>(qf, hash_w, hash_b, out);
}

// Round 2
// 1182.606 us; speedup vs baseline: 2.2017x; 2.2017x over previous
//
#include <hip/hip_runtime.h>
#include <hip/hip_bf16.h>
#include <math.h>

#define D_ 512
#define K_ 8
#define L_ 64
#define Q_ 4096
#define C_ 4096
#define N_ (C_ * K_)   // 32768 rows of P viewed as [N][D]

#define TS 64
#define BK 16

typedef short short8 __attribute__((ext_vector_type(8)));
typedef float f32x4 __attribute__((ext_vector_type(4)));

static __device__ __forceinline__ unsigned short bf16_bits(float x) {
    __hip_bfloat16 h = __float2bfloat16(x);
    return *reinterpret_cast<unsigned short*>(&h);
}

#define ASYNC_COPY16(gp, lp)                                                        \
    __builtin_amdgcn_global_load_lds((const __attribute__((address_space(1))) void*)(gp), \
                                     (__attribute__((address_space(3))) void*)(lp), \
                                     16, 0, 0)

// ---------------------------------------------------------------------------
// Kernel 1: transpose M[i,j,k] (strides D*K, K, 1) -> Mt[k][i][j]
// ---------------------------------------------------------------------------
__global__ void transpose_M(const float* __restrict__ M, float* __restrict__ Mt) {
    int idx = blockIdx.x * blockDim.x + threadIdx.x;
    int j = idx % D_;
    int i = (idx / D_) % D_;
    int k = idx / (D_ * D_);
    Mt[idx] = M[(i * D_ + j) * K_ + k];
}

// ---------------------------------------------------------------------------
// Kernel 1b: split query into bf16 hi/lo pair (x = hi + lo, each bf16)
// ---------------------------------------------------------------------------
__global__ void split_query(const float* __restrict__ x,
                            unsigned short* __restrict__ hi,
                            unsigned short* __restrict__ lo) {
    int i = blockIdx.x * blockDim.x + threadIdx.x;   // over Q*D
    float v = x[i];
    __hip_bfloat16 h = __float2bfloat16(v);
    float r = v - __bfloat162float(h);
    hi[i] = *reinterpret_cast<unsigned short*>(&h);
    lo[i] = bf16_bits(r);
}

// ---------------------------------------------------------------------------
// Kernel 2: P[c][k*D+j] = sum_i class[c,i] * Mt[k][i][j], written as split
// bf16 hi/lo arrays (fp32 P is never materialized). Flat layout == [C*K][D].
// ---------------------------------------------------------------------------
__launch_bounds__(256)
__global__ void gemm_P(const float* __restrict__ A,    // class [C][D]
                       const float* __restrict__ Mt,   // [K][D][D]
                       unsigned short* __restrict__ Ph,
                       unsigned short* __restrict__ Pl) {
    __shared__ float As[BK][TS];
    __shared__ float Bs[BK][TS];
    const int n0 = blockIdx.x * TS;      // over K*D
    const int c0 = blockIdx.y * TS;
    const int kslab = n0 / D_;
    const int j0 = n0 % D_;
    const float* B = Mt + (size_t)kslab * D_ * D_;
    const int tid = threadIdx.x;
    const int tx = tid % 16, ty = tid / 16;
    float acc[4][4] = {};
    for (int i0 = 0; i0 < D_; i0 += BK) {
        {
            int r = tid / 4, cg = tid % 4;
            const float4 av = *(const float4*)&A[(size_t)(c0 + r) * D_ + i0 + cg * 4];
            As[cg * 4 + 0][r] = av.x; As[cg * 4 + 1][r] = av.y;
            As[cg * 4 + 2][r] = av.z; As[cg * 4 + 3][r] = av.w;
        }
        {
            int r = tid / 16, cg = tid % 16;
            const float4 bv = *(const float4*)&B[(size_t)(i0 + r) * D_ + j0 + cg * 4];
            *(float4*)&Bs[r][cg * 4] = bv;
        }
        __syncthreads();
#pragma unroll
        for (int i = 0; i < BK; ++i) {
            float4 a = *(const float4*)&As[i][ty * 4];
            float4 b = *(const float4*)&Bs[i][tx * 4];
            float av[4] = {a.x, a.y, a.z, a.w};
            float bv[4] = {b.x, b.y, b.z, b.w};
#pragma unroll
            for (int u = 0; u < 4; ++u)
#pragma unroll
                for (int v = 0; v < 4; ++v) acc[u][v] += av[u] * bv[v];
        }
        __syncthreads();
    }
#pragma unroll
    for (int u = 0; u < 4; ++u) {
        size_t base = (size_t)(c0 + ty * 4 + u) * (K_ * D_) + n0 + tx * 4;
        ushort4 oh, ol;
        float* ac = acc[u];
        unsigned short hb[4], lb[4];
#pragma unroll
        for (int v = 0; v < 4; ++v) {
            __hip_bfloat16 h = __float2bfloat16(ac[v]);
            float r = ac[v] - __bfloat162float(h);
            hb[v] = *reinterpret_cast<unsigned short*>(&h);
            lb[v] = bf16_bits(r);
        }
        oh.x = hb[0]; oh.y = hb[1]; oh.z = hb[2]; oh.w = hb[3];
        ol.x = lb[0]; ol.y = lb[1]; ol.z = lb[2]; ol.w = lb[3];
        *(ushort4*)&Ph[base] = oh;
        *(ushort4*)&Pl[base] = ol;
    }
}

// ---------------------------------------------------------------------------
// Kernel 3: fused bilinear + relu + score reduction via bf16x3 split MFMA.
// other[q][c] = sb + sum_k sw[k] * relu( sum_j query[q][j] * P[c*8+k][j] )
// 128x128 tile, BK=32, 16x16x32 bf16 MFMA, global_load_lds staging.
// ---------------------------------------------------------------------------
#define BM 128
#define BN 128
#define BKK 32

__launch_bounds__(256)
__global__ void bilinear_mfma(const unsigned short* __restrict__ Qh,
                              const unsigned short* __restrict__ Ql,
                              const unsigned short* __restrict__ Ph,
                              const unsigned short* __restrict__ Pl,
                              const float* __restrict__ sw,
                              const float* __restrict__ sb,
                              float* __restrict__ other) {
    __shared__ __attribute__((aligned(16))) unsigned short Ah[BM * BKK];
    __shared__ __attribute__((aligned(16))) unsigned short Al[BM * BKK];
    __shared__ __attribute__((aligned(16))) unsigned short Bh[BN * BKK];
    __shared__ __attribute__((aligned(16))) unsigned short Bl[BN * BKK];

    const int tid = threadIdx.x;
    const int lane = tid & 63;
    const int wid = tid >> 6;
    const int q0 = blockIdx.y * BM;      // query rows
    const int n0 = blockIdx.x * BN;      // P rows (class*8+k)
    const int wr = (wid >> 1) * 64;      // wave row offset in tile
    const int wc = (wid & 1) * 64;       // wave col offset in tile

    f32x4 acc[4][4] = {};   // acc[mi][ni], mi over q, ni over n

    for (int j0 = 0; j0 < D_; j0 += BKK) {
#pragma unroll
        for (int h = 0; h < 2; ++h) {
            const int i2 = h * 256 + tid;
            const int r = i2 >> 2, cc = i2 & 3;
            const int ldsoff = (h * 256 + (tid & ~63)) * 8;   // elems, wave-uniform
            const size_t goffA = (size_t)(q0 + r) * D_ + j0 + cc * 8;
            const size_t goffB = (size_t)(n0 + r) * D_ + j0 + cc * 8;
            ASYNC_COPY16(Qh + goffA, Ah + ldsoff);
            ASYNC_COPY16(Ql + goffA, Al + ldsoff);
            ASYNC_COPY16(Ph + goffB, Bh + ldsoff);
            ASYNC_COPY16(Pl + goffB, Bl + ldsoff);
        }
        __syncthreads();

        const int fr = lane & 15;
        const int fq = lane >> 4;
        short8 afh[4], afl[4], bfh[4], bfl[4];
#pragma unroll
        for (int t = 0; t < 4; ++t) {
            afh[t] = *(const short8*)&Ah[(wr + t * 16 + fr) * BKK + fq * 8];
            afl[t] = *(const short8*)&Al[(wr + t * 16 + fr) * BKK + fq * 8];
            bfh[t] = *(const short8*)&Bh[(wc + t * 16 + fr) * BKK + fq * 8];
            bfl[t] = *(const short8*)&Bl[(wc + t * 16 + fr) * BKK + fq * 8];
        }
#pragma unroll
        for (int mi = 0; mi < 4; ++mi)
#pragma unroll
            for (int ni = 0; ni < 4; ++ni) {
                acc[mi][ni] = __builtin_amdgcn_mfma_f32_16x16x32_bf16(afh[mi], bfh[ni], acc[mi][ni], 0, 0, 0);
                acc[mi][ni] = __builtin_amdgcn_mfma_f32_16x16x32_bf16(afh[mi], bfl[ni], acc[mi][ni], 0, 0, 0);
                acc[mi][ni] = __builtin_amdgcn_mfma_f32_16x16x32_bf16(afl[mi], bfh[ni], acc[mi][ni], 0, 0, 0);
            }
        __syncthreads();
    }

    // Epilogue: C/D layout: col = lane&15 (n), row = (lane>>4)*4 + reg (q).
    // k = n & 7 (all tile offsets are multiples of 16). Reduce over the 8
    // lanes that share a class (cols 0-7 / 8-15 of each 16-tile).
    const float wk = sw[lane & 7];
    const float bias = sb[0];
#pragma unroll
    for (int mi = 0; mi < 4; ++mi)
#pragma unroll
        for (int ni = 0; ni < 4; ++ni) {
#pragma unroll
            for (int r = 0; r < 4; ++r) {
                float v = wk * fmaxf(acc[mi][ni][r], 0.f);
                v += __shfl_xor(v, 1);
                v += __shfl_xor(v, 2);
                v += __shfl_xor(v, 4);
                if ((lane & 7) == 0) {
                    int q = q0 + wr + mi * 16 + (lane >> 4) * 4 + r;
                    int c = (n0 + wc + ni * 16 + (lane & 15)) >> 3;
                    other[(size_t)q * C_ + c] = v + bias;
                }
            }
        }
}

// ---------------------------------------------------------------------------
// Kernel 4: in-place row softmax over C.
// ---------------------------------------------------------------------------
__launch_bounds__(256)
__global__ void softmax_rows(float* __restrict__ base) {
    const int q = blockIdx.x;
    float* row = base + (size_t)q * C_;
    const int tid = threadIdx.x;
    __shared__ float red[4];
    float m = -1e30f;
    for (int i = tid; i < C_; i += 256) m = fmaxf(m, row[i]);
#pragma unroll
    for (int off = 32; off; off >>= 1) m = fmaxf(m, __shfl_down(m, off));
    if ((tid & 63) == 0) red[tid >> 6] = m;
    __syncthreads();
    m = fmaxf(fmaxf(red[0], red[1]), fmaxf(red[2], red[3]));
    __syncthreads();
    float s = 0.f;
    for (int i = tid; i < C_; i += 256) {
        float e = __expf(row[i] - m);
        row[i] = e;
        s += e;
    }
#pragma unroll
    for (int off = 32; off; off >>= 1) s += __shfl_down(s, off);
    if ((tid & 63) == 0) red[tid >> 6] = s;
    __syncthreads();
    const float inv = 1.f / (red[0] + red[1] + red[2] + red[3]);
    for (int i = tid; i < C_; i += 256) row[i] *= inv;
}

// ---------------------------------------------------------------------------
// Kernel 5: qf[q][d] = sum_c probs[q][c] * class[c][d] + query[q][d]
// ---------------------------------------------------------------------------
__launch_bounds__(256)
__global__ void gemm_qf(const float* __restrict__ A,   // probs [Q][C]
                        const float* __restrict__ B,   // class [C][D]
                        const float* __restrict__ Qv,  // query [Q][D]
                        float* __restrict__ qf) {      // [Q][D]
    __shared__ float As[BK][TS];
    __shared__ float Bs[BK][TS];
    const int d0 = blockIdx.x * TS;
    const int q0 = blockIdx.y * TS;
    const int tid = threadIdx.x;
    const int tx = tid % 16, ty = tid / 16;
    float acc[4][4] = {};
    for (int c0 = 0; c0 < C_; c0 += BK) {
        {
            int r = tid / 4, cg = tid % 4;
            const float4 av = *(const float4*)&A[(size_t)(q0 + r) * C_ + c0 + cg * 4];
            As[cg * 4 + 0][r] = av.x; As[cg * 4 + 1][r] = av.y;
            As[cg * 4 + 2][r] = av.z; As[cg * 4 + 3][r] = av.w;
        }
        {
            int r = tid / 16, cg = tid % 16;
            const float4 bv = *(const float4*)&B[(size_t)(c0 + r) * D_ + d0 + cg * 4];
            *(float4*)&Bs[r][cg * 4] = bv;
        }
        __syncthreads();
#pragma unroll
        for (int i = 0; i < BK; ++i) {
            float4 a = *(const float4*)&As[i][ty * 4];
            float4 b = *(const float4*)&Bs[i][tx * 4];
            float av[4] = {a.x, a.y, a.z, a.w};
            float bv[4] = {b.x, b.y, b.z, b.w};
#pragma unroll
            for (int u = 0; u < 4; ++u)
#pragma unroll
                for (int v = 0; v < 4; ++v) acc[u][v] += av[u] * bv[v];
        }
        __syncthreads();
    }
#pragma unroll
    for (int u = 0; u < 4; ++u) {
        const int q = q0 + ty * 4 + u;
        const float4 qv = *(const float4*)&Qv[(size_t)q * D_ + d0 + tx * 4];
        float4 o = {acc[u][0] + qv.x, acc[u][1] + qv.y,
                    acc[u][2] + qv.z, acc[u][3] + qv.w};
        *(float4*)&qf[(size_t)q * D_ + d0 + tx * 4] = o;
    }
}

// ---------------------------------------------------------------------------
// Kernel 6: hash[q][l] = tanh( sum_d qf[q][d]*hash_w[l][d] + hash_b[l] )
// ---------------------------------------------------------------------------
__launch_bounds__(256)
__global__ void hash_kernel(const float* __restrict__ qf,
                            const float* __restrict__ hw,
                            const float* __restrict__ hb,
                            float* __restrict__ out) {
    __shared__ float sqf[4 * D_];
    const int q0 = blockIdx.x * 4;
    const int tid = threadIdx.x;
    {
        const float4* src = (const float4*)&qf[(size_t)q0 * D_];
        float4* dst = (float4*)sqf;
#pragma unroll
        for (int it = 0; it < 2; ++it) dst[tid + it * 256] = src[tid + it * 256];
    }
    __syncthreads();
    const int l = tid % L_;
    const int qi = tid / L_;
    float s = hb[l];
    const float* wrow = &hw[(size_t)l * D_];
    const float* xrow = &sqf[qi * D_];
#pragma unroll 4
    for (int d = 0; d < D_; d += 4) {
        float4 w4 = *(const float4*)&wrow[d];
        float4 x4 = *(const float4*)&xrow[d];
        s += x4.x * w4.x + x4.y * w4.y + x4.z * w4.z + x4.w * w4.w;
    }
    out[(size_t)(q0 + qi) * L_ + l] = tanhf(s);
}

// ---------------------------------------------------------------------------
extern "C" void kernel_launch(void* const* d_in, const int* in_sizes, int n_in,
                              void* d_out, int out_size, void* d_ws, size_t ws_size,
                              hipStream_t stream) {
    const float* class_v = (const float*)d_in[0];
    const float* query_v = (const float*)d_in[1];
    const float* M       = (const float*)d_in[2];
    const float* score_w = (const float*)d_in[3];
    const float* score_b = (const float*)d_in[4];
    const float* hash_w  = (const float*)d_in[5];
    const float* hash_b  = (const float*)d_in[6];
    float* out = (float*)d_out;

    // Workspace layout (142.6 MB total, same as round-1 footprint):
    //   [0,   32M)  P_hi  (C*K*D bf16)
    //   [32M, 64M)  P_lo
    //   [64M, 128M) other (Q*C fp32)
    //   [128M,136M) scratch: Mt (fp32, dead after gemm_P) ->
    //               Qh/Ql (bf16, dead after bilinear) -> qf (fp32)
    char* base = (char*)d_ws;
    unsigned short* Ph = (unsigned short*)base;
    unsigned short* Pl = (unsigned short*)(base + (size_t)33554432);
    float* other       = (float*)(base + (size_t)67108864);
    char* scratch      = base + (size_t)134217728;
    float* Mt          = (float*)scratch;
    unsigned short* Qh = (unsigned short*)scratch;
    unsigned short* Ql = (unsigned short*)(scratch + (size_t)4194304);
    float* qf          = (float*)scratch;

    transpose_M<<<(D_ * D_ * K_) / 256, 256, 0, stream>>>(M, Mt);
    gemm_P<<<dim3((K_ * D_) / TS, C_ / TS), 256, 0, stream>>>(class_v, Mt, Ph, Pl);
    split_query<<<(Q_ * D_) / 256, 256, 0, stream>>>(query_v, Qh, Ql);
    bilinear_mfma<<<dim3(N_ / BN, Q_ / BM), 256, 0, stream>>>(Qh, Ql, Ph, Pl,
                                                              score_w, score_b, other);
    softmax_rows<<<Q_, 256, 0, stream>>>(other);
    gemm_qf<<<dim3(D_ / TS, Q_ / TS), 256, 0, stream>>>(other, class_v, query_v, qf);
    hash_kernel<<<Q_ / 4, 256, 0, stream>>>(qf, hash_w, hash_b, out);
}

// Round 3
// 898.069 us; speedup vs baseline: 2.8993x; 1.3168x over previous
//
#include <hip/hip_runtime.h>
#include <hip/hip_bf16.h>
#include <math.h>

#define D_ 512
#define K_ 8
#define L_ 64
#define Q_ 4096
#define C_ 4096
#define N_ (C_ * K_)   // 32768 rows of P viewed as [N][D]

typedef short short8 __attribute__((ext_vector_type(8)));
typedef float f32x4 __attribute__((ext_vector_type(4)));

static __device__ __forceinline__ void split2(float v, unsigned short& h, unsigned short& l) {
    __hip_bfloat16 hh = __float2bfloat16(v);
    float r = v - __bfloat162float(hh);
    __hip_bfloat16 ll = __float2bfloat16(r);
    h = *reinterpret_cast<unsigned short*>(&hh);
    l = *reinterpret_cast<unsigned short*>(&ll);
}

#define ASYNC_COPY16(gp, lp)                                                        \
    __builtin_amdgcn_global_load_lds((const __attribute__((address_space(1))) void*)(gp), \
                                     (__attribute__((address_space(3))) void*)(lp), \
                                     16, 0, 0)

// ---------------------------------------------------------------------------
// Prep kernels: transposes + fp32 -> bf16 hi/lo splits
// ---------------------------------------------------------------------------
__global__ void transpose_M_split(const float* __restrict__ M,
                                  unsigned short* __restrict__ Mh,
                                  unsigned short* __restrict__ Ml) {
    int idx = blockIdx.x * blockDim.x + threadIdx.x;   // over (K*D)*D, out [k*D+j][i]
    int i = idx & (D_ - 1);
    int n2 = idx >> 9;
    int j = n2 & (D_ - 1);
    int k = n2 >> 9;
    float v = M[((size_t)i * D_ + j) * K_ + k];
    split2(v, Mh[idx], Ml[idx]);
}

__global__ void split_f32(const float* __restrict__ x,
                          unsigned short* __restrict__ hi,
                          unsigned short* __restrict__ lo) {
    int i = blockIdx.x * blockDim.x + threadIdx.x;
    split2(x[i], hi[i], lo[i]);
}

__global__ void transpose_split_classT(const float* __restrict__ x,   // class [C][D]
                                       unsigned short* __restrict__ Th,
                                       unsigned short* __restrict__ Tl) {
    int idx = blockIdx.x * blockDim.x + threadIdx.x;   // out [d][c]
    int c = idx & (C_ - 1);
    int d = idx >> 12;
    float v = x[(size_t)c * D_ + d];
    split2(v, Th[idx], Tl[idx]);
}

// ---------------------------------------------------------------------------
// Shared MFMA NT-GEMM core: out128x128 tile, BK=32, bf16x3 split product.
// A [rows m][kd], B [rows n][kd], both split hi/lo, contraction contiguous.
// XOR swizzle ((r>>1)&3) on 8-elem column groups kills LDS bank conflicts.
// ---------------------------------------------------------------------------
#define BM 128
#define BN 128
#define BKK 32

__device__ __forceinline__ void mfma_nt_core(
    const unsigned short* __restrict__ Agh, const unsigned short* __restrict__ Agl,
    const unsigned short* __restrict__ Bgh, const unsigned short* __restrict__ Bgl,
    int lda, int ldb, int kd, int m0, int n0,
    unsigned short* Ah, unsigned short* Al, unsigned short* Bh, unsigned short* Bl,
    int tid, f32x4 acc[4][4]) {
    const int lane = tid & 63;
    const int wid = tid >> 6;
    const int wr = (wid >> 1) * 64;
    const int wc = (wid & 1) * 64;
    for (int j0 = 0; j0 < kd; j0 += BKK) {
#pragma unroll
        for (int h = 0; h < 2; ++h) {
            const int i2 = h * 256 + tid;
            const int r = i2 >> 2;
            const int cg = (i2 & 3) ^ ((r >> 1) & 3);     // swizzled col group
            const int ldsoff = (h * 256 + (tid & ~63)) * 8;  // wave-uniform base
            const size_t goffA = (size_t)(m0 + r) * lda + j0 + cg * 8;
            const size_t goffB = (size_t)(n0 + r) * ldb + j0 + cg * 8;
            ASYNC_COPY16(Agh + goffA, Ah + ldsoff);
            ASYNC_COPY16(Agl + goffA, Al + ldsoff);
            ASYNC_COPY16(Bgh + goffB, Bh + ldsoff);
            ASYNC_COPY16(Bgl + goffB, Bl + ldsoff);
        }
        __syncthreads();
        const int fr = lane & 15;
        const int fq = lane >> 4;
        const int co = (fq ^ ((fr >> 1) & 3)) * 8;        // read-side swizzle
        short8 afh[4], afl[4], bfh[4], bfl[4];
#pragma unroll
        for (int t = 0; t < 4; ++t) {
            afh[t] = *(const short8*)&Ah[(wr + t * 16 + fr) * BKK + co];
            afl[t] = *(const short8*)&Al[(wr + t * 16 + fr) * BKK + co];
            bfh[t] = *(const short8*)&Bh[(wc + t * 16 + fr) * BKK + co];
            bfl[t] = *(const short8*)&Bl[(wc + t * 16 + fr) * BKK + co];
        }
#pragma unroll
        for (int mi = 0; mi < 4; ++mi)
#pragma unroll
            for (int ni = 0; ni < 4; ++ni) {
                acc[mi][ni] = __builtin_amdgcn_mfma_f32_16x16x32_bf16(afh[mi], bfh[ni], acc[mi][ni], 0, 0, 0);
                acc[mi][ni] = __builtin_amdgcn_mfma_f32_16x16x32_bf16(afh[mi], bfl[ni], acc[mi][ni], 0, 0, 0);
                acc[mi][ni] = __builtin_amdgcn_mfma_f32_16x16x32_bf16(afl[mi], bfh[ni], acc[mi][ni], 0, 0, 0);
            }
        __syncthreads();
    }
}

#define MFMA_PROLOGUE                                                          \
    __shared__ __attribute__((aligned(16))) unsigned short Ah[BM * BKK];       \
    __shared__ __attribute__((aligned(16))) unsigned short Al[BM * BKK];       \
    __shared__ __attribute__((aligned(16))) unsigned short Bh[BN * BKK];       \
    __shared__ __attribute__((aligned(16))) unsigned short Bl[BN * BKK];       \
    const int tid = threadIdx.x;                                               \
    const int lane = tid & 63;                                                 \
    const int wid = tid >> 6;                                                  \
    const int wr = (wid >> 1) * 64;                                            \
    const int wc = (wid & 1) * 64;                                             \
    f32x4 acc[4][4] = {};

// ---------------------------------------------------------------------------
// gemm_P: Ph/Pl[c][k*D+j] = split( sum_i class[c,i] * M[i,j,k] )
// A = class split [C][D]; B = Mt2 split [K*D][D].
// ---------------------------------------------------------------------------
__launch_bounds__(256)
__global__ void gemm_P_mfma(const unsigned short* __restrict__ Chh,
                            const unsigned short* __restrict__ Cll,
                            const unsigned short* __restrict__ Mh,
                            const unsigned short* __restrict__ Ml,
                            unsigned short* __restrict__ Ph,
                            unsigned short* __restrict__ Pl) {
    MFMA_PROLOGUE
    const int n0 = blockIdx.x * BN;   // over K*D
    const int c0 = blockIdx.y * BM;
    mfma_nt_core(Chh, Cll, Mh, Ml, D_, D_, D_, c0, n0, Ah, Al, Bh, Bl, tid, acc);
#pragma unroll
    for (int mi = 0; mi < 4; ++mi)
#pragma unroll
        for (int ni = 0; ni < 4; ++ni)
#pragma unroll
            for (int r = 0; r < 4; ++r) {
                int c = c0 + wr + mi * 16 + (lane >> 4) * 4 + r;
                int n2 = n0 + wc + ni * 16 + (lane & 15);
                size_t o = (size_t)c * (K_ * D_) + n2;
                split2(acc[mi][ni][r], Ph[o], Pl[o]);
            }
}

// ---------------------------------------------------------------------------
// bilinear: other[q][c] = sb + sum_k sw[k]*relu( sum_j query[q,j]*P[c*8+k][j] )
// ---------------------------------------------------------------------------
__launch_bounds__(256)
__global__ void bilinear_mfma(const unsigned short* __restrict__ Qh,
                              const unsigned short* __restrict__ Ql,
                              const unsigned short* __restrict__ Ph,
                              const unsigned short* __restrict__ Pl,
                              const float* __restrict__ sw,
                              const float* __restrict__ sb,
                              float* __restrict__ other) {
    MFMA_PROLOGUE
    const int n0 = blockIdx.x * BN;   // over N = C*K
    const int q0 = blockIdx.y * BM;
    mfma_nt_core(Qh, Ql, Ph, Pl, D_, D_, D_, q0, n0, Ah, Al, Bh, Bl, tid, acc);
    const float wk = sw[lane & 7];
    const float bias = sb[0];
#pragma unroll
    for (int mi = 0; mi < 4; ++mi)
#pragma unroll
        for (int ni = 0; ni < 4; ++ni)
#pragma unroll
            for (int r = 0; r < 4; ++r) {
                float v = wk * fmaxf(acc[mi][ni][r], 0.f);
                v += __shfl_xor(v, 1);
                v += __shfl_xor(v, 2);
                v += __shfl_xor(v, 4);
                if ((lane & 7) == 0) {
                    int q = q0 + wr + mi * 16 + (lane >> 4) * 4 + r;
                    int c = (n0 + wc + ni * 16 + (lane & 15)) >> 3;
                    other[(size_t)q * C_ + c] = v + bias;
                }
            }
}

// ---------------------------------------------------------------------------
// gemm_qf: qf[q][d] = sum_c probs[q][c]*class[c][d] + query[q][d]
// A = probs split [Q][C]; B = classT split [D][C].
// ---------------------------------------------------------------------------
__launch_bounds__(256)
__global__ void gemm_qf_mfma(const unsigned short* __restrict__ Sh,
                             const unsigned short* __restrict__ Sl,
                             const unsigned short* __restrict__ Th,
                             const unsigned short* __restrict__ Tl,
                             const float* __restrict__ Qv,
                             float* __restrict__ qf) {
    MFMA_PROLOGUE
    const int n0 = blockIdx.x * BN;   // over D
    const int q0 = blockIdx.y * BM;
    mfma_nt_core(Sh, Sl, Th, Tl, C_, C_, C_, q0, n0, Ah, Al, Bh, Bl, tid, acc);
#pragma unroll
    for (int mi = 0; mi < 4; ++mi)
#pragma unroll
        for (int ni = 0; ni < 4; ++ni)
#pragma unroll
            for (int r = 0; r < 4; ++r) {
                int q = q0 + wr + mi * 16 + (lane >> 4) * 4 + r;
                int d = n0 + wc + ni * 16 + (lane & 15);
                size_t o = (size_t)q * D_ + d;
                qf[o] = acc[mi][ni][r] + Qv[o];
            }
}

// ---------------------------------------------------------------------------
// Softmax over C per row; emits probs as split bf16 hi/lo. Row in registers.
// ---------------------------------------------------------------------------
__launch_bounds__(256)
__global__ void softmax_split(const float* __restrict__ other,
                              unsigned short* __restrict__ Sh,
                              unsigned short* __restrict__ Sl) {
    const int q = blockIdx.x;
    const float* row = other + (size_t)q * C_;
    const int tid = threadIdx.x;
    __shared__ float red[4];
    float v[16];
    float m = -1e30f;
#pragma unroll
    for (int it = 0; it < 16; ++it) {
        v[it] = row[tid + it * 256];
        m = fmaxf(m, v[it]);
    }
#pragma unroll
    for (int off = 32; off; off >>= 1) m = fmaxf(m, __shfl_down(m, off));
    if ((tid & 63) == 0) red[tid >> 6] = m;
    __syncthreads();
    m = fmaxf(fmaxf(red[0], red[1]), fmaxf(red[2], red[3]));
    __syncthreads();
    float s = 0.f;
#pragma unroll
    for (int it = 0; it < 16; ++it) {
        v[it] = __expf(v[it] - m);
        s += v[it];
    }
#pragma unroll
    for (int off = 32; off; off >>= 1) s += __shfl_down(s, off);
    if ((tid & 63) == 0) red[tid >> 6] = s;
    __syncthreads();
    const float inv = 1.f / (red[0] + red[1] + red[2] + red[3]);
#pragma unroll
    for (int it = 0; it < 16; ++it) {
        size_t o = (size_t)q * C_ + tid + it * 256;
        split2(v[it] * inv, Sh[o], Sl[o]);
    }
}

// ---------------------------------------------------------------------------
// hash[q][l] = tanh( sum_d qf[q][d]*hash_w[l][d] + hash_b[l] )
// ---------------------------------------------------------------------------
__launch_bounds__(256)
__global__ void hash_kernel(const float* __restrict__ qf,
                            const float* __restrict__ hw,
                            const float* __restrict__ hb,
                            float* __restrict__ out) {
    __shared__ float sqf[4 * D_];
    const int q0 = blockIdx.x * 4;
    const int tid = threadIdx.x;
    {
        const float4* src = (const float4*)&qf[(size_t)q0 * D_];
        float4* dst = (float4*)sqf;
#pragma unroll
        for (int it = 0; it < 2; ++it) dst[tid + it * 256] = src[tid + it * 256];
    }
    __syncthreads();
    const int l = tid % L_;
    const int qi = tid / L_;
    float s = hb[l];
    const float* wrow = &hw[(size_t)l * D_];
    const float* xrow = &sqf[qi * D_];
#pragma unroll 4
    for (int d = 0; d < D_; d += 4) {
        float4 w4 = *(const float4*)&wrow[d];
        float4 x4 = *(const float4*)&xrow[d];
        s += x4.x * w4.x + x4.y * w4.y + x4.z * w4.z + x4.w * w4.w;
    }
    out[(size_t)(q0 + qi) * L_ + l] = tanhf(s);
}

// ---------------------------------------------------------------------------
extern "C" void kernel_launch(void* const* d_in, const int* in_sizes, int n_in,
                              void* d_out, int out_size, void* d_ws, size_t ws_size,
                              hipStream_t stream) {
    const float* class_v = (const float*)d_in[0];
    const float* query_v = (const float*)d_in[1];
    const float* M       = (const float*)d_in[2];
    const float* score_w = (const float*)d_in[3];
    const float* score_b = (const float*)d_in[4];
    const float* hash_w  = (const float*)d_in[5];
    const float* hash_b  = (const float*)d_in[6];
    float* out = (float*)d_out;

    // Workspace (142.6 MB, same footprint as rounds 1-2):
    //  [0,     33.5M)  Ph            -> Sh (probs hi) after softmax
    //  [33.5M, 67M)    Pl            -> Sl (probs lo)
    //  [67M,   134.2M) other (fp32 Q*C logits)
    //                  prep aliases (dead once bilinear writes other):
    //                    Mt2h/Mt2l at +0/+4.2M, Ch/Cl at +8.4M/+12.6M
    //                  post-softmax alias: qf (fp32 Q*D) at +0
    //  [134.2M,142.6M) scratch: Qh/Ql (bf16)  -> Th/Tl (classT) after bilinear
    char* base = (char*)d_ws;
    unsigned short* Ph = (unsigned short*)base;
    unsigned short* Pl = (unsigned short*)(base + (size_t)33554432);
    char* oreg          = base + (size_t)67108864;
    float* other        = (float*)oreg;
    unsigned short* Mh  = (unsigned short*)oreg;
    unsigned short* Ml  = (unsigned short*)(oreg + (size_t)4194304);
    unsigned short* Chh = (unsigned short*)(oreg + (size_t)8388608);
    unsigned short* Cll = (unsigned short*)(oreg + (size_t)12582912);
    float* qf           = (float*)oreg;
    char* scratch = base + (size_t)134217728;
    unsigned short* Qh = (unsigned short*)scratch;
    unsigned short* Ql = (unsigned short*)(scratch + (size_t)4194304);
    unsigned short* Th = (unsigned short*)scratch;
    unsigned short* Tl = (unsigned short*)(scratch + (size_t)4194304);
    unsigned short* Sh = Ph;
    unsigned short* Sl = Pl;

    transpose_M_split<<<(K_ * D_ * D_) / 256, 256, 0, stream>>>(M, Mh, Ml);
    split_f32<<<(C_ * D_) / 256, 256, 0, stream>>>(class_v, Chh, Cll);
    split_f32<<<(Q_ * D_) / 256, 256, 0, stream>>>(query_v, Qh, Ql);
    gemm_P_mfma<<<dim3((K_ * D_) / BN, C_ / BM), 256, 0, stream>>>(Chh, Cll, Mh, Ml, Ph, Pl);
    bilinear_mfma<<<dim3(N_ / BN, Q_ / BM), 256, 0, stream>>>(Qh, Ql, Ph, Pl,
                                                              score_w, score_b, other);
    softmax_split<<<Q_, 256, 0, stream>>>(other, Sh, Sl);
    transpose_split_classT<<<(C_ * D_) / 256, 256, 0, stream>>>(class_v, Th, Tl);
    gemm_qf_mfma<<<dim3(D_ / BN, Q_ / BM), 256, 0, stream>>>(Sh, Sl, Th, Tl, query_v, qf);
    hash_kernel<<<Q_ / 4, 256, 0, stream>>>(qf, hash_w, hash_b, out);
}

// Round 4
// 779.025 us; speedup vs baseline: 3.3424x; 1.1528x over previous
//
#include <hip/hip_runtime.h>
#include <hip/hip_bf16.h>
#include <math.h>

#define D_ 512
#define K_ 8
#define L_ 64
#define Q_ 4096
#define C_ 4096
#define N_ (C_ * K_)   // 32768 rows of P viewed as [N][D]

typedef short short8 __attribute__((ext_vector_type(8)));
typedef float f32x4 __attribute__((ext_vector_type(4)));

static __device__ __forceinline__ void split2(float v, unsigned short& h, unsigned short& l) {
    __hip_bfloat16 hh = __float2bfloat16(v);
    float r = v - __bfloat162float(hh);
    __hip_bfloat16 ll = __float2bfloat16(r);
    h = *reinterpret_cast<unsigned short*>(&hh);
    l = *reinterpret_cast<unsigned short*>(&ll);
}

#define ASYNC_COPY16(gp, lp)                                                        \
    __builtin_amdgcn_global_load_lds((const __attribute__((address_space(1))) void*)(gp), \
                                     (__attribute__((address_space(3))) void*)(lp), \
                                     16, 0, 0)

// ---------------------------------------------------------------------------
// Prep kernels: transposes + fp32 -> bf16 hi/lo splits
// ---------------------------------------------------------------------------
__global__ void transpose_M_split(const float* __restrict__ M,
                                  unsigned short* __restrict__ Mh,
                                  unsigned short* __restrict__ Ml) {
    int idx = blockIdx.x * blockDim.x + threadIdx.x;   // over (K*D)*D, out [k*D+j][i]
    int i = idx & (D_ - 1);
    int n2 = idx >> 9;
    int j = n2 & (D_ - 1);
    int k = n2 >> 9;
    float v = M[((size_t)i * D_ + j) * K_ + k];
    split2(v, Mh[idx], Ml[idx]);
}

__global__ void split_f32(const float* __restrict__ x,
                          unsigned short* __restrict__ hi,
                          unsigned short* __restrict__ lo) {
    int i = blockIdx.x * blockDim.x + threadIdx.x;
    split2(x[i], hi[i], lo[i]);
}

__global__ void transpose_split_classT(const float* __restrict__ x,   // class [C][D]
                                       unsigned short* __restrict__ Th,
                                       unsigned short* __restrict__ Tl) {
    int idx = blockIdx.x * blockDim.x + threadIdx.x;   // out [d][c]
    int c = idx & (C_ - 1);
    int d = idx >> 12;
    float v = x[(size_t)c * D_ + d];
    split2(v, Th[idx], Tl[idx]);
}

// ---------------------------------------------------------------------------
// Pipelined MFMA NT-GEMM core. Block tile 128(M) x 128(N), BK=32, bf16x3.
// Wave tile 128x32 (full M rows, 32 cols per wave -> no cross-wave B dup).
// A staged via global_load_lds into double-buffered LDS (swizzled);
// B loaded straight global->VGPR (16B/lane, one full 64B line per 16 rows).
// Single barrier per K-iter; next iter's A-stage + B-loads issued BEFORE the
// MFMA block so the barrier's vmcnt(0) drain overlaps ~931 cyc of MFMA.
// ---------------------------------------------------------------------------
#define BM 128
#define BN 128
#define BNW 32
#define BKK 32

__device__ __forceinline__ void mfma_core(
    const unsigned short* __restrict__ Agh, const unsigned short* __restrict__ Agl,
    const unsigned short* __restrict__ Bgh, const unsigned short* __restrict__ Bgl,
    int lda, int ldb, int kd, int m0, int n0,
    unsigned short (*Ahb)[BM * BKK], unsigned short (*Alb)[BM * BKK],
    f32x4 acc[8][2]) {
    const int tid = threadIdx.x;
    const int lane = tid & 63;
    const int wid = tid >> 6;
    const int fr = lane & 15;
    const int fq = lane >> 4;
    const int co = (fq ^ ((fr >> 1) & 3)) * 8;

    const unsigned short* bh0 = Bgh + (size_t)(n0 + wid * BNW + fr) * ldb + fq * 8;
    const unsigned short* bl0 = Bgl + (size_t)(n0 + wid * BNW + fr) * ldb + fq * 8;

    short8 bh[2][2], bl[2][2];

    // stage iter 0 A into buf 0; load iter 0 B
#pragma unroll
    for (int h = 0; h < 2; ++h) {
        const int i2 = h * 256 + tid;
        const int r = i2 >> 2;
        const int cg = (i2 & 3) ^ ((r >> 1) & 3);
        const int ldsoff = (h * 256 + (tid & ~63)) * 8;
        const size_t go = (size_t)(m0 + r) * lda + cg * 8;
        ASYNC_COPY16(Agh + go, &Ahb[0][ldsoff]);
        ASYNC_COPY16(Agl + go, &Alb[0][ldsoff]);
    }
    bh[0][0] = *(const short8*)(bh0);
    bh[0][1] = *(const short8*)(bh0 + 16 * (size_t)ldb);
    bl[0][0] = *(const short8*)(bl0);
    bl[0][1] = *(const short8*)(bl0 + 16 * (size_t)ldb);
    __syncthreads();

    const int niter = kd / BKK;
#pragma unroll 2
    for (int it = 0; it < niter; ++it) {
        const int cur = it & 1, nxt = cur ^ 1;
        if (it + 1 < niter) {
            const int j0 = (it + 1) * BKK;
#pragma unroll
            for (int h = 0; h < 2; ++h) {
                const int i2 = h * 256 + tid;
                const int r = i2 >> 2;
                const int cg = (i2 & 3) ^ ((r >> 1) & 3);
                const int ldsoff = (h * 256 + (tid & ~63)) * 8;
                const size_t go = (size_t)(m0 + r) * lda + j0 + cg * 8;
                ASYNC_COPY16(Agh + go, &Ahb[nxt][ldsoff]);
                ASYNC_COPY16(Agl + go, &Alb[nxt][ldsoff]);
            }
            bh[nxt][0] = *(const short8*)(bh0 + j0);
            bh[nxt][1] = *(const short8*)(bh0 + 16 * (size_t)ldb + j0);
            bl[nxt][0] = *(const short8*)(bl0 + j0);
            bl[nxt][1] = *(const short8*)(bl0 + 16 * (size_t)ldb + j0);
        }
#pragma unroll
        for (int mi = 0; mi < 8; ++mi) {
            const short8 ah = *(const short8*)&Ahb[cur][(mi * 16 + fr) * BKK + co];
            const short8 al = *(const short8*)&Alb[cur][(mi * 16 + fr) * BKK + co];
#pragma unroll
            for (int ni = 0; ni < 2; ++ni) {
                acc[mi][ni] = __builtin_amdgcn_mfma_f32_16x16x32_bf16(ah, bh[cur][ni], acc[mi][ni], 0, 0, 0);
                acc[mi][ni] = __builtin_amdgcn_mfma_f32_16x16x32_bf16(ah, bl[cur][ni], acc[mi][ni], 0, 0, 0);
                acc[mi][ni] = __builtin_amdgcn_mfma_f32_16x16x32_bf16(al, bh[cur][ni], acc[mi][ni], 0, 0, 0);
            }
        }
        __syncthreads();
    }
}

#define CORE_PROLOGUE                                                            \
    __shared__ __attribute__((aligned(16))) unsigned short Ahb[2][BM * BKK];     \
    __shared__ __attribute__((aligned(16))) unsigned short Alb[2][BM * BKK];     \
    const int tid = threadIdx.x;                                                 \
    const int lane = tid & 63;                                                   \
    const int wid = tid >> 6;                                                    \
    const int fr = lane & 15;                                                    \
    const int fq = lane >> 4;                                                    \
    f32x4 acc[8][2] = {};                                                        \
    (void)tid;

// ---------------------------------------------------------------------------
// gemm_P: Ph/Pl[c][k*D+j] = split( sum_i class[c,i] * M[i,j,k] )
// ---------------------------------------------------------------------------
__launch_bounds__(256, 3)
__global__ void gemm_P_mfma(const unsigned short* __restrict__ Chh,
                            const unsigned short* __restrict__ Cll,
                            const unsigned short* __restrict__ Mh,
                            const unsigned short* __restrict__ Ml,
                            unsigned short* __restrict__ Ph,
                            unsigned short* __restrict__ Pl) {
    CORE_PROLOGUE
    const int n0 = blockIdx.x * BN;   // over K*D
    const int c0 = blockIdx.y * BM;
    mfma_core(Chh, Cll, Mh, Ml, D_, D_, D_, c0, n0, Ahb, Alb, acc);
#pragma unroll
    for (int mi = 0; mi < 8; ++mi)
#pragma unroll
        for (int ni = 0; ni < 2; ++ni)
#pragma unroll
            for (int r = 0; r < 4; ++r) {
                int c = c0 + mi * 16 + fq * 4 + r;
                int n2 = n0 + wid * BNW + ni * 16 + fr;
                size_t o = (size_t)c * (K_ * D_) + n2;
                split2(acc[mi][ni][r], Ph[o], Pl[o]);
            }
}

// ---------------------------------------------------------------------------
// bilinear: other[q][c] = sb + sum_k sw[k]*relu( sum_j query[q,j]*P[c*8+k][j] )
// ---------------------------------------------------------------------------
__launch_bounds__(256, 3)
__global__ void bilinear_mfma(const unsigned short* __restrict__ Qh,
                              const unsigned short* __restrict__ Ql,
                              const unsigned short* __restrict__ Ph,
                              const unsigned short* __restrict__ Pl,
                              const float* __restrict__ sw,
                              const float* __restrict__ sb,
                              float* __restrict__ other) {
    CORE_PROLOGUE
    const int n0 = blockIdx.x * BN;   // over N = C*K
    const int q0 = blockIdx.y * BM;
    mfma_core(Qh, Ql, Ph, Pl, D_, D_, D_, q0, n0, Ahb, Alb, acc);
    const float wk = sw[lane & 7];
    const float bias = sb[0];
#pragma unroll
    for (int mi = 0; mi < 8; ++mi)
#pragma unroll
        for (int ni = 0; ni < 2; ++ni)
#pragma unroll
            for (int r = 0; r < 4; ++r) {
                float v = wk * fmaxf(acc[mi][ni][r], 0.f);
                v += __shfl_xor(v, 1);
                v += __shfl_xor(v, 2);
                v += __shfl_xor(v, 4);
                if ((lane & 7) == 0) {
                    int q = q0 + mi * 16 + fq * 4 + r;
                    int c = (n0 + wid * BNW + ni * 16 + fr) >> 3;
                    other[(size_t)q * C_ + c] = v + bias;
                }
            }
}

// ---------------------------------------------------------------------------
// gemm_qf (split-K over grid.z): qfp[q][d] = sum_{c in half} probs[q][c]*class[c][d]
// ---------------------------------------------------------------------------
__launch_bounds__(256, 3)
__global__ void gemm_qf_mfma(const unsigned short* __restrict__ Sh,
                             const unsigned short* __restrict__ Sl,
                             const unsigned short* __restrict__ Th,
                             const unsigned short* __restrict__ Tl,
                             float* __restrict__ qfp0,
                             float* __restrict__ qfp1) {
    CORE_PROLOGUE
    const int n0 = blockIdx.x * BN;   // over D
    const int q0 = blockIdx.y * BM;
    const int zoff = blockIdx.z * (C_ / 2);
    float* qfp = blockIdx.z ? qfp1 : qfp0;
    mfma_core(Sh + zoff, Sl + zoff, Th + zoff, Tl + zoff,
              C_, C_, C_ / 2, q0, n0, Ahb, Alb, acc);
#pragma unroll
    for (int mi = 0; mi < 8; ++mi)
#pragma unroll
        for (int ni = 0; ni < 2; ++ni)
#pragma unroll
            for (int r = 0; r < 4; ++r) {
                int q = q0 + mi * 16 + fq * 4 + r;
                int d = n0 + wid * BNW + ni * 16 + fr;
                qfp[(size_t)q * D_ + d] = acc[mi][ni][r];
            }
}

// ---------------------------------------------------------------------------
// Softmax over C per row; emits probs as split bf16 hi/lo. Row in registers.
// ---------------------------------------------------------------------------
__launch_bounds__(256)
__global__ void softmax_split(const float* __restrict__ other,
                              unsigned short* __restrict__ Sh,
                              unsigned short* __restrict__ Sl) {
    const int q = blockIdx.x;
    const float* row = other + (size_t)q * C_;
    const int tid = threadIdx.x;
    __shared__ float red[4];
    float v[16];
    float m = -1e30f;
#pragma unroll
    for (int it = 0; it < 16; ++it) {
        v[it] = row[tid + it * 256];
        m = fmaxf(m, v[it]);
    }
#pragma unroll
    for (int off = 32; off; off >>= 1) m = fmaxf(m, __shfl_down(m, off));
    if ((tid & 63) == 0) red[tid >> 6] = m;
    __syncthreads();
    m = fmaxf(fmaxf(red[0], red[1]), fmaxf(red[2], red[3]));
    __syncthreads();
    float s = 0.f;
#pragma unroll
    for (int it = 0; it < 16; ++it) {
        v[it] = __expf(v[it] - m);
        s += v[it];
    }
#pragma unroll
    for (int off = 32; off; off >>= 1) s += __shfl_down(s, off);
    if ((tid & 63) == 0) red[tid >> 6] = s;
    __syncthreads();
    const float inv = 1.f / (red[0] + red[1] + red[2] + red[3]);
#pragma unroll
    for (int it = 0; it < 16; ++it) {
        size_t o = (size_t)q * C_ + tid + it * 256;
        split2(v[it] * inv, Sh[o], Sl[o]);
    }
}

// ---------------------------------------------------------------------------
// hash[q][l] = tanh( sum_d (qfp0+qfp1+query)[q][d]*hash_w[l][d] + hash_b[l] )
// ---------------------------------------------------------------------------
__launch_bounds__(256)
__global__ void hash_kernel(const float* __restrict__ qfp0,
                            const float* __restrict__ qfp1,
                            const float* __restrict__ Qv,
                            const float* __restrict__ hw,
                            const float* __restrict__ hb,
                            float* __restrict__ out) {
    __shared__ float sqf[4 * D_];
    const int q0 = blockIdx.x * 4;
    const int tid = threadIdx.x;
    {
        const float4* s0 = (const float4*)&qfp0[(size_t)q0 * D_];
        const float4* s1 = (const float4*)&qfp1[(size_t)q0 * D_];
        const float4* s2 = (const float4*)&Qv[(size_t)q0 * D_];
        float4* dst = (float4*)sqf;
#pragma unroll
        for (int it = 0; it < 2; ++it) {
            int i = tid + it * 256;
            float4 a = s0[i], b = s1[i], c = s2[i];
            float4 o = {a.x + b.x + c.x, a.y + b.y + c.y,
                        a.z + b.z + c.z, a.w + b.w + c.w};
            dst[i] = o;
        }
    }
    __syncthreads();
    const int l = tid % L_;
    const int qi = tid / L_;
    float s = hb[l];
    const float* wrow = &hw[(size_t)l * D_];
    const float* xrow = &sqf[qi * D_];
#pragma unroll 4
    for (int d = 0; d < D_; d += 4) {
        float4 w4 = *(const float4*)&wrow[d];
        float4 x4 = *(const float4*)&xrow[d];
        s += x4.x * w4.x + x4.y * w4.y + x4.z * w4.z + x4.w * w4.w;
    }
    out[(size_t)(q0 + qi) * L_ + l] = tanhf(s);
}

// ---------------------------------------------------------------------------
extern "C" void kernel_launch(void* const* d_in, const int* in_sizes, int n_in,
                              void* d_out, int out_size, void* d_ws, size_t ws_size,
                              hipStream_t stream) {
    const float* class_v = (const float*)d_in[0];
    const float* query_v = (const float*)d_in[1];
    const float* M       = (const float*)d_in[2];
    const float* score_w = (const float*)d_in[3];
    const float* score_b = (const float*)d_in[4];
    const float* hash_w  = (const float*)d_in[5];
    const float* hash_b  = (const float*)d_in[6];
    float* out = (float*)d_out;

    // Workspace (142.6 MB, same footprint as rounds 1-3):
    //  [0,     33.5M)  Ph            -> Sh (probs hi) after softmax
    //  [33.5M, 67M)    Pl            -> Sl (probs lo)
    //  [67M,   134.2M) other (fp32 Q*C logits)
    //                  prep aliases (dead once bilinear writes other):
    //                    Mh/Ml at +0/+4.2M, Ch/Cl at +8.4M/+12.6M
    //                  post-softmax alias: qfp0 at +0, qfp1 at +8.4M
    //  [134.2M,142.6M) scratch: Qh/Ql (bf16)  -> Th/Tl (classT) after bilinear
    char* base = (char*)d_ws;
    unsigned short* Ph = (unsigned short*)base;
    unsigned short* Pl = (unsigned short*)(base + (size_t)33554432);
    char* oreg          = base + (size_t)67108864;
    float* other        = (float*)oreg;
    unsigned short* Mh  = (unsigned short*)oreg;
    unsigned short* Ml  = (unsigned short*)(oreg + (size_t)4194304);
    unsigned short* Chh = (unsigned short*)(oreg + (size_t)8388608);
    unsigned short* Cll = (unsigned short*)(oreg + (size_t)12582912);
    float* qfp0         = (float*)oreg;
    float* qfp1         = (float*)(oreg + (size_t)8388608);
    char* scratch = base + (size_t)134217728;
    unsigned short* Qh = (unsigned short*)scratch;
    unsigned short* Ql = (unsigned short*)(scratch + (size_t)4194304);
    unsigned short* Th = (unsigned short*)scratch;
    unsigned short* Tl = (unsigned short*)(scratch + (size_t)4194304);
    unsigned short* Sh = Ph;
    unsigned short* Sl = Pl;

    transpose_M_split<<<(K_ * D_ * D_) / 256, 256, 0, stream>>>(M, Mh, Ml);
    split_f32<<<(C_ * D_) / 256, 256, 0, stream>>>(class_v, Chh, Cll);
    split_f32<<<(Q_ * D_) / 256, 256, 0, stream>>>(query_v, Qh, Ql);
    gemm_P_mfma<<<dim3((K_ * D_) / BN, C_ / BM), 256, 0, stream>>>(Chh, Cll, Mh, Ml, Ph, Pl);
    bilinear_mfma<<<dim3(N_ / BN, Q_ / BM), 256, 0, stream>>>(Qh, Ql, Ph, Pl,
                                                              score_w, score_b, other);
    softmax_split<<<Q_, 256, 0, stream>>>(other, Sh, Sl);
    transpose_split_classT<<<(C_ * D_) / 256, 256, 0, stream>>>(class_v, Th, Tl);
    gemm_qf_mfma<<<dim3(D_ / BN, Q_ / BM, 2), 256, 0, stream>>>(Sh, Sl, Th, Tl, qfp0, qfp1);
    hash_kernel<<<Q_ / 4, 256, 0, stream>>>(qfp0, qfp1, query_v, hash_w, hash_b, out);
}

// Round 5
// 758.870 us; speedup vs baseline: 3.4311x; 1.0266x over previous
//
#include <hip/hip_runtime.h>
#include <hip/hip_bf16.h>
#include <math.h>

#define D_ 512
#define K_ 8
#define L_ 64
#define Q_ 4096
#define C_ 4096
#define N_ (C_ * K_)   // 32768 rows of P viewed as [N][D]

typedef short short8 __attribute__((ext_vector_type(8)));
typedef float f32x4 __attribute__((ext_vector_type(4)));

static __device__ __forceinline__ void split2(float v, unsigned short& h, unsigned short& l) {
    __hip_bfloat16 hh = __float2bfloat16(v);
    float r = v - __bfloat162float(hh);
    __hip_bfloat16 ll = __float2bfloat16(r);
    h = *reinterpret_cast<unsigned short*>(&hh);
    l = *reinterpret_cast<unsigned short*>(&ll);
}

#define ASYNC_COPY16(gp, lp)                                                        \
    __builtin_amdgcn_global_load_lds((const __attribute__((address_space(1))) void*)(gp), \
                                     (__attribute__((address_space(3))) void*)(lp), \
                                     16, 0, 0)

// ---------------------------------------------------------------------------
// Prep kernels: transposes + fp32 -> bf16 hi/lo splits
// ---------------------------------------------------------------------------
__global__ void transpose_M_split(const float* __restrict__ M,
                                  unsigned short* __restrict__ Mh,
                                  unsigned short* __restrict__ Ml) {
    int idx = blockIdx.x * blockDim.x + threadIdx.x;   // over (K*D)*D, out [k*D+j][i]
    int i = idx & (D_ - 1);
    int n2 = idx >> 9;
    int j = n2 & (D_ - 1);
    int k = n2 >> 9;
    float v = M[((size_t)i * D_ + j) * K_ + k];
    split2(v, Mh[idx], Ml[idx]);
}

__global__ void split_f32(const float* __restrict__ x,
                          unsigned short* __restrict__ hi,
                          unsigned short* __restrict__ lo) {
    int i = blockIdx.x * blockDim.x + threadIdx.x;
    split2(x[i], hi[i], lo[i]);
}

__global__ void transpose_split_classT(const float* __restrict__ x,   // class [C][D]
                                       unsigned short* __restrict__ Th,
                                       unsigned short* __restrict__ Tl) {
    int idx = blockIdx.x * blockDim.x + threadIdx.x;   // out [d][c]
    int c = idx & (C_ - 1);
    int d = idx >> 12;
    float v = x[(size_t)c * D_ + d];
    split2(v, Th[idx], Tl[idx]);
}

// ---------------------------------------------------------------------------
// Pipelined MFMA NT-GEMM core. Block tile 128(M) x 128(N), BK=32, bf16x3.
// Wave tile 128x32; A via double-buffered LDS (global_load_lds, swizzled);
// B direct global->VGPR. Single barrier per K-iter; next iter's loads issue
// before the MFMA block so the barrier's vmcnt(0) drain overlaps MFMA.
// ---------------------------------------------------------------------------
#define BM 128
#define BN 128
#define BNW 32
#define BKK 32

__device__ __forceinline__ void mfma_core(
    const unsigned short* __restrict__ Agh, const unsigned short* __restrict__ Agl,
    const unsigned short* __restrict__ Bgh, const unsigned short* __restrict__ Bgl,
    int lda, int ldb, int kd, int m0, int n0,
    unsigned short (*Ahb)[BM * BKK], unsigned short (*Alb)[BM * BKK],
    f32x4 acc[8][2]) {
    const int tid = threadIdx.x;
    const int lane = tid & 63;
    const int wid = tid >> 6;
    const int fr = lane & 15;
    const int fq = lane >> 4;
    const int co = (fq ^ ((fr >> 1) & 3)) * 8;

    const unsigned short* bh0 = Bgh + (size_t)(n0 + wid * BNW + fr) * ldb + fq * 8;
    const unsigned short* bl0 = Bgl + (size_t)(n0 + wid * BNW + fr) * ldb + fq * 8;

    short8 bh[2][2], bl[2][2];

    // stage iter 0 A into buf 0; load iter 0 B
#pragma unroll
    for (int h = 0; h < 2; ++h) {
        const int i2 = h * 256 + tid;
        const int r = i2 >> 2;
        const int cg = (i2 & 3) ^ ((r >> 1) & 3);
        const int ldsoff = (h * 256 + (tid & ~63)) * 8;
        const size_t go = (size_t)(m0 + r) * lda + cg * 8;
        ASYNC_COPY16(Agh + go, &Ahb[0][ldsoff]);
        ASYNC_COPY16(Agl + go, &Alb[0][ldsoff]);
    }
    bh[0][0] = *(const short8*)(bh0);
    bh[0][1] = *(const short8*)(bh0 + 16 * (size_t)ldb);
    bl[0][0] = *(const short8*)(bl0);
    bl[0][1] = *(const short8*)(bl0 + 16 * (size_t)ldb);
    __syncthreads();

    const int niter = kd / BKK;
#pragma unroll 2
    for (int it = 0; it < niter; ++it) {
        const int cur = it & 1, nxt = cur ^ 1;
        if (it + 1 < niter) {
            const int j0 = (it + 1) * BKK;
#pragma unroll
            for (int h = 0; h < 2; ++h) {
                const int i2 = h * 256 + tid;
                const int r = i2 >> 2;
                const int cg = (i2 & 3) ^ ((r >> 1) & 3);
                const int ldsoff = (h * 256 + (tid & ~63)) * 8;
                const size_t go = (size_t)(m0 + r) * lda + j0 + cg * 8;
                ASYNC_COPY16(Agh + go, &Ahb[nxt][ldsoff]);
                ASYNC_COPY16(Agl + go, &Alb[nxt][ldsoff]);
            }
            bh[nxt][0] = *(const short8*)(bh0 + j0);
            bh[nxt][1] = *(const short8*)(bh0 + 16 * (size_t)ldb + j0);
            bl[nxt][0] = *(const short8*)(bl0 + j0);
            bl[nxt][1] = *(const short8*)(bl0 + 16 * (size_t)ldb + j0);
        }
#pragma unroll
        for (int mi = 0; mi < 8; ++mi) {
            const short8 ah = *(const short8*)&Ahb[cur][(mi * 16 + fr) * BKK + co];
            const short8 al = *(const short8*)&Alb[cur][(mi * 16 + fr) * BKK + co];
#pragma unroll
            for (int ni = 0; ni < 2; ++ni) {
                acc[mi][ni] = __builtin_amdgcn_mfma_f32_16x16x32_bf16(ah, bh[cur][ni], acc[mi][ni], 0, 0, 0);
                acc[mi][ni] = __builtin_amdgcn_mfma_f32_16x16x32_bf16(ah, bl[cur][ni], acc[mi][ni], 0, 0, 0);
                acc[mi][ni] = __builtin_amdgcn_mfma_f32_16x16x32_bf16(al, bh[cur][ni], acc[mi][ni], 0, 0, 0);
            }
        }
        __syncthreads();
    }
}

#define CORE_PROLOGUE                                                            \
    __shared__ __attribute__((aligned(16))) unsigned short Ahb[2][BM * BKK];     \
    __shared__ __attribute__((aligned(16))) unsigned short Alb[2][BM * BKK];     \
    const int tid = threadIdx.x;                                                 \
    const int lane = tid & 63;                                                   \
    const int wid = tid >> 6;                                                    \
    const int fr = lane & 15;                                                    \
    const int fq = lane >> 4;                                                    \
    f32x4 acc[8][2] = {};                                                        \
    (void)tid;

// ---------------------------------------------------------------------------
// gemm_P: Ph/Pl[c][k*D+j] = split( sum_i class[c,i] * M[i,j,k] )
// ---------------------------------------------------------------------------
__launch_bounds__(256, 4)
__global__ void gemm_P_mfma(const unsigned short* __restrict__ Chh,
                            const unsigned short* __restrict__ Cll,
                            const unsigned short* __restrict__ Mh,
                            const unsigned short* __restrict__ Ml,
                            unsigned short* __restrict__ Ph,
                            unsigned short* __restrict__ Pl) {
    CORE_PROLOGUE
    const int n0 = blockIdx.x * BN;   // over K*D
    const int c0 = blockIdx.y * BM;
    mfma_core(Chh, Cll, Mh, Ml, D_, D_, D_, c0, n0, Ahb, Alb, acc);
#pragma unroll
    for (int mi = 0; mi < 8; ++mi)
#pragma unroll
        for (int ni = 0; ni < 2; ++ni)
#pragma unroll
            for (int r = 0; r < 4; ++r) {
                int c = c0 + mi * 16 + fq * 4 + r;
                int n2 = n0 + wid * BNW + ni * 16 + fr;
                size_t o = (size_t)c * (K_ * D_) + n2;
                split2(acc[mi][ni][r], Ph[o], Pl[o]);
            }
}

// ---------------------------------------------------------------------------
// bilinear: other[q][c] = sb + sum_k sw[k]*relu( sum_j query[q,j]*P[c*8+k][j] )
// Grid is q-fastest: co-resident blocks share one B-panel (L2/L3 locality).
// ---------------------------------------------------------------------------
__launch_bounds__(256, 4)
__global__ void bilinear_mfma(const unsigned short* __restrict__ Qh,
                              const unsigned short* __restrict__ Ql,
                              const unsigned short* __restrict__ Ph,
                              const unsigned short* __restrict__ Pl,
                              const float* __restrict__ sw,
                              const float* __restrict__ sb,
                              float* __restrict__ other) {
    CORE_PROLOGUE
    const int q0 = blockIdx.x * BM;   // q-fastest
    const int n0 = blockIdx.y * BN;   // over N = C*K
    mfma_core(Qh, Ql, Ph, Pl, D_, D_, D_, q0, n0, Ahb, Alb, acc);
    const float wk = sw[lane & 7];
    const float bias = sb[0];
#pragma unroll
    for (int mi = 0; mi < 8; ++mi)
#pragma unroll
        for (int ni = 0; ni < 2; ++ni)
#pragma unroll
            for (int r = 0; r < 4; ++r) {
                float v = wk * fmaxf(acc[mi][ni][r], 0.f);
                v += __shfl_xor(v, 1);
                v += __shfl_xor(v, 2);
                v += __shfl_xor(v, 4);
                if ((lane & 7) == 0) {
                    int q = q0 + mi * 16 + fq * 4 + r;
                    int c = (n0 + wid * BNW + ni * 16 + fr) >> 3;
                    other[(size_t)q * C_ + c] = v + bias;
                }
            }
}

// ---------------------------------------------------------------------------
// gemm_qf (split-K=4 over grid.z): qfp[z][q][d] = sum_{c in quarter} probs*classT
// ---------------------------------------------------------------------------
__launch_bounds__(256, 4)
__global__ void gemm_qf_mfma(const unsigned short* __restrict__ Sh,
                             const unsigned short* __restrict__ Sl,
                             const unsigned short* __restrict__ Th,
                             const unsigned short* __restrict__ Tl,
                             float* __restrict__ qfp_base) {
    CORE_PROLOGUE
    const int n0 = blockIdx.x * BN;   // over D
    const int q0 = blockIdx.y * BM;
    const int zoff = blockIdx.z * (C_ / 4);
    float* qfp = qfp_base + (size_t)blockIdx.z * Q_ * D_;
    mfma_core(Sh + zoff, Sl + zoff, Th + zoff, Tl + zoff,
              C_, C_, C_ / 4, q0, n0, Ahb, Alb, acc);
#pragma unroll
    for (int mi = 0; mi < 8; ++mi)
#pragma unroll
        for (int ni = 0; ni < 2; ++ni)
#pragma unroll
            for (int r = 0; r < 4; ++r) {
                int q = q0 + mi * 16 + fq * 4 + r;
                int d = n0 + wid * BNW + ni * 16 + fr;
                qfp[(size_t)q * D_ + d] = acc[mi][ni][r];
            }
}

// ---------------------------------------------------------------------------
// Softmax over C per row; emits probs as split bf16 hi/lo. Row in registers.
// ---------------------------------------------------------------------------
__launch_bounds__(256)
__global__ void softmax_split(const float* __restrict__ other,
                              unsigned short* __restrict__ Sh,
                              unsigned short* __restrict__ Sl) {
    const int q = blockIdx.x;
    const float* row = other + (size_t)q * C_;
    const int tid = threadIdx.x;
    __shared__ float red[4];
    float v[16];
    float m = -1e30f;
#pragma unroll
    for (int it = 0; it < 16; ++it) {
        v[it] = row[tid + it * 256];
        m = fmaxf(m, v[it]);
    }
#pragma unroll
    for (int off = 32; off; off >>= 1) m = fmaxf(m, __shfl_down(m, off));
    if ((tid & 63) == 0) red[tid >> 6] = m;
    __syncthreads();
    m = fmaxf(fmaxf(red[0], red[1]), fmaxf(red[2], red[3]));
    __syncthreads();
    float s = 0.f;
#pragma unroll
    for (int it = 0; it < 16; ++it) {
        v[it] = __expf(v[it] - m);
        s += v[it];
    }
#pragma unroll
    for (int off = 32; off; off >>= 1) s += __shfl_down(s, off);
    if ((tid & 63) == 0) red[tid >> 6] = s;
    __syncthreads();
    const float inv = 1.f / (red[0] + red[1] + red[2] + red[3]);
#pragma unroll
    for (int it = 0; it < 16; ++it) {
        size_t o = (size_t)q * C_ + tid + it * 256;
        split2(v[it] * inv, Sh[o], Sl[o]);
    }
}

// ---------------------------------------------------------------------------
// hash[q][l] = tanh( sum_d (sum_z qfp[z] + query)[q][d]*hash_w[l][d] + hb[l] )
// ---------------------------------------------------------------------------
__launch_bounds__(256)
__global__ void hash_kernel(const float* __restrict__ qfp_base,
                            const float* __restrict__ Qv,
                            const float* __restrict__ hw,
                            const float* __restrict__ hb,
                            float* __restrict__ out) {
    __shared__ float sqf[4 * D_];
    const int q0 = blockIdx.x * 4;
    const int tid = threadIdx.x;
    {
        const float4* s0 = (const float4*)&qfp_base[(size_t)q0 * D_];
        const float4* s1 = (const float4*)&qfp_base[(size_t)Q_ * D_ + q0 * D_];
        const float4* s2 = (const float4*)&qfp_base[(size_t)2 * Q_ * D_ + q0 * D_];
        const float4* s3 = (const float4*)&qfp_base[(size_t)3 * Q_ * D_ + q0 * D_];
        const float4* s4 = (const float4*)&Qv[(size_t)q0 * D_];
        float4* dst = (float4*)sqf;
#pragma unroll
        for (int it = 0; it < 2; ++it) {
            int i = tid + it * 256;
            float4 a = s0[i], b = s1[i], c = s2[i], d = s3[i], e = s4[i];
            float4 o = {a.x + b.x + c.x + d.x + e.x, a.y + b.y + c.y + d.y + e.y,
                        a.z + b.z + c.z + d.z + e.z, a.w + b.w + c.w + d.w + e.w};
            dst[i] = o;
        }
    }
    __syncthreads();
    const int l = tid % L_;
    const int qi = tid / L_;
    float s = hb[l];
    const float* wrow = &hw[(size_t)l * D_];
    const float* xrow = &sqf[qi * D_];
#pragma unroll 4
    for (int d = 0; d < D_; d += 4) {
        float4 w4 = *(const float4*)&wrow[d];
        float4 x4 = *(const float4*)&xrow[d];
        s += x4.x * w4.x + x4.y * w4.y + x4.z * w4.z + x4.w * w4.w;
    }
    out[(size_t)(q0 + qi) * L_ + l] = tanhf(s);
}

// ---------------------------------------------------------------------------
extern "C" void kernel_launch(void* const* d_in, const int* in_sizes, int n_in,
                              void* d_out, int out_size, void* d_ws, size_t ws_size,
                              hipStream_t stream) {
    const float* class_v = (const float*)d_in[0];
    const float* query_v = (const float*)d_in[1];
    const float* M       = (const float*)d_in[2];
    const float* score_w = (const float*)d_in[3];
    const float* score_b = (const float*)d_in[4];
    const float* hash_w  = (const float*)d_in[5];
    const float* hash_b  = (const float*)d_in[6];
    float* out = (float*)d_out;

    // Workspace (142.6 MB, same footprint as rounds 1-4):
    //  [0,     33.5M)  Ph            -> Sh (probs hi) after softmax
    //  [33.5M, 67M)    Pl            -> Sl (probs lo)
    //  [67M,   134.2M) other (fp32 Q*C logits)
    //                  prep aliases (dead once bilinear writes other):
    //                    Mh/Ml at +0/+4.2M, Ch/Cl at +8.4M/+12.6M
    //                  post-softmax alias: qfp[4] at +0 (4 x 8.4M fp32)
    //  [134.2M,142.6M) scratch: Qh/Ql (bf16)  -> Th/Tl (classT) after bilinear
    char* base = (char*)d_ws;
    unsigned short* Ph = (unsigned short*)base;
    unsigned short* Pl = (unsigned short*)(base + (size_t)33554432);
    char* oreg          = base + (size_t)67108864;
    float* other        = (float*)oreg;
    unsigned short* Mh  = (unsigned short*)oreg;
    unsigned short* Ml  = (unsigned short*)(oreg + (size_t)4194304);
    unsigned short* Chh = (unsigned short*)(oreg + (size_t)8388608);
    unsigned short* Cll = (unsigned short*)(oreg + (size_t)12582912);
    float* qfp          = (float*)oreg;
    char* scratch = base + (size_t)134217728;
    unsigned short* Qh = (unsigned short*)scratch;
    unsigned short* Ql = (unsigned short*)(scratch + (size_t)4194304);
    unsigned short* Th = (unsigned short*)scratch;
    unsigned short* Tl = (unsigned short*)(scratch + (size_t)4194304);
    unsigned short* Sh = Ph;
    unsigned short* Sl = Pl;

    transpose_M_split<<<(K_ * D_ * D_) / 256, 256, 0, stream>>>(M, Mh, Ml);
    split_f32<<<(C_ * D_) / 256, 256, 0, stream>>>(class_v, Chh, Cll);
    split_f32<<<(Q_ * D_) / 256, 256, 0, stream>>>(query_v, Qh, Ql);
    gemm_P_mfma<<<dim3((K_ * D_) / BN, C_ / BM), 256, 0, stream>>>(Chh, Cll, Mh, Ml, Ph, Pl);
    bilinear_mfma<<<dim3(Q_ / BM, N_ / BN), 256, 0, stream>>>(Qh, Ql, Ph, Pl,
                                                              score_w, score_b, other);
    softmax_split<<<Q_, 256, 0, stream>>>(other, Sh, Sl);
    transpose_split_classT<<<(C_ * D_) / 256, 256, 0, stream>>>(class_v, Th, Tl);
    gemm_qf_mfma<<<dim3(D_ / BN, Q_ / BM, 4), 256, 0, stream>>>(Sh, Sl, Th, Tl, qfp);
    hash_kernel<<<Q_ / 4, 256, 0, stream>>>(qfp, query_v, hash_w, hash_b, out);
}